// Round 2
// baseline (146.935 us; speedup 1.0000x reference)
//
#include <hip/hip_runtime.h>
#include <cstdint>
#include <cstddef>

#define NROWS 100000
#define FIN 512
#define HIDDEN 256
#define NCLS 50

typedef __attribute__((ext_vector_type(8))) short s16x8;
typedef __attribute__((ext_vector_type(4))) float f32x4;

__device__ __forceinline__ unsigned short f2bf(float f) {
  unsigned int u = __float_as_uint(f);
  u += 0x7fffu + ((u >> 16) & 1u);
  return (unsigned short)(u >> 16);
}

__device__ __forceinline__ void gload_lds16(const void* g, void* l) {
  __builtin_amdgcn_global_load_lds(
      (const __attribute__((address_space(1))) void*)g,
      (__attribute__((address_space(3))) void*)l, 16, 0, 0);
}

// prep: w1t[n][k] = bf16(W1[k][n])  [256][512]   (blocks 0..31, LDS transpose)
//       w2t[c][k] = bf16(W2[k][c]), c>=50 -> 0   [64][256]   (blocks 32..35)
__global__ __launch_bounds__(256) void prep_kernel(
    const float* __restrict__ W1, const float* __restrict__ W2,
    unsigned short* __restrict__ w1t, unsigned short* __restrict__ w2t) {
  __shared__ float tile[64][65];
  const int b = blockIdx.x, t = threadIdx.x;
  if (b < 32) {
    const int k0 = (b >> 2) * 64, n0 = (b & 3) * 64;
    const int rq = t >> 6, col = t & 63;
#pragma unroll
    for (int i = 0; i < 16; ++i) {
      int row = i * 4 + rq;
      tile[row][col] = W1[(size_t)(k0 + row) * HIDDEN + n0 + col];
    }
    __syncthreads();
#pragma unroll
    for (int i = 0; i < 16; ++i) {
      int n = i * 4 + rq;
      w1t[(size_t)(n0 + n) * FIN + k0 + col] = f2bf(tile[col][n]);
    }
  } else {
    const int b2i = b - 32;  // 0..3, k-range
#pragma unroll
    for (int i = 0; i < 16; ++i) {
      int idx = t + i * 256;          // 0..4095
      int c = idx >> 6;               // 0..63
      int k = b2i * 64 + (idx & 63);  // 0..255
      float v = (c < NCLS) ? W2[(size_t)k * NCLS + c] : 0.0f;
      w2t[(size_t)c * HIDDEN + k] = f2bf(v);
    }
  }
}

// Fused: out = log_softmax(relu(x@W1+b1) @ W2 + b2)
// 512 threads = 8 waves (4M x 2N), block tile 128 rows x 256 cols, BK=64.
// A: direct global fp32->bf16 in regs (prefetch 1 K-step ahead).
// B: w1t staged to LDS via global_load_lds, double-buffered, XOR-chunk swizzle
//    (pre-swizzled global source + swizzled ds_read -> conflict-free).
// Epilogue: h tile -> LDS (swizzled), GEMM2 (K=256) vs w2t from L2, log-softmax.
__global__ __launch_bounds__(512) void fused_kernel(
    const float* __restrict__ x, const unsigned short* __restrict__ w1t,
    const unsigned short* __restrict__ w2t, const float* __restrict__ b1,
    const float* __restrict__ b2, float* __restrict__ out) {
  __shared__ unsigned short smem[32768];  // 64KB: B dbuf (2x32KB) / h tile (64KB)

  const int t = threadIdx.x;
  const int lane = t & 63, wid = t >> 6;
  const int q = lane & 15, half = lane >> 4;
  const int wr = wid >> 1, wc = wid & 1;
  const int bm = blockIdx.x;
  const int rowbase = bm * 128 + wr * 32;

  // per-lane A row pointers (clamped tail)
  const float* aptr[2];
#pragma unroll
  for (int m = 0; m < 2; ++m) {
    int r = rowbase + m * 16 + q;
    if (r > NROWS - 1) r = NROWS - 1;
    aptr[m] = x + (size_t)r * FIN;
  }

  // ---- B staging: 2048 chunks of 16B per buffer, 4 per thread ----
  // LDS chunk (row, s) holds global chunk (row, s^(row&7)).
  auto stage_B = [&](unsigned short* buf, int k0) {
#pragma unroll
    for (int i = 0; i < 4; ++i) {
      int c = t + i * 512;
      int r = c >> 3, s = c & 7;
      gload_lds16(w1t + (size_t)r * FIN + k0 + ((s ^ (r & 7)) << 3), buf + c * 8);
    }
  };

  float4 Areg[8];
  auto load_A = [&](int k0) {
#pragma unroll
    for (int m = 0; m < 2; ++m)
#pragma unroll
      for (int kk = 0; kk < 2; ++kk) {
        const float* p = aptr[m] + k0 + kk * 32 + half * 8;
        Areg[m * 4 + kk * 2 + 0] = ((const float4*)p)[0];
        Areg[m * 4 + kk * 2 + 1] = ((const float4*)p)[1];
      }
  };

  f32x4 acc[2][8];
  const f32x4 z4 = {0.f, 0.f, 0.f, 0.f};
#pragma unroll
  for (int m = 0; m < 2; ++m)
#pragma unroll
    for (int n = 0; n < 8; ++n) acc[m][n] = z4;

  stage_B(smem, 0);
  load_A(0);
  __syncthreads();  // buf0 + Areg(0) resident

  for (int k0 = 0; k0 < FIN; k0 += 64) {
    const int cur = (k0 >> 6) & 1;
    unsigned short* bufc = smem + cur * 16384;

    if (k0 + 64 < FIN) stage_B(smem + (cur ^ 1) * 16384, k0 + 64);

    // convert this step's A regs to fragments (before reloading Areg)
    s16x8 afrag[2][2];
#pragma unroll
    for (int m = 0; m < 2; ++m)
#pragma unroll
      for (int kk = 0; kk < 2; ++kk) {
        const float4 a0 = Areg[m * 4 + kk * 2 + 0];
        const float4 a1 = Areg[m * 4 + kk * 2 + 1];
        s16x8 v;
        v[0] = (short)f2bf(a0.x); v[1] = (short)f2bf(a0.y);
        v[2] = (short)f2bf(a0.z); v[3] = (short)f2bf(a0.w);
        v[4] = (short)f2bf(a1.x); v[5] = (short)f2bf(a1.y);
        v[6] = (short)f2bf(a1.z); v[7] = (short)f2bf(a1.w);
        afrag[m][kk] = v;
      }

    if (k0 + 64 < FIN) load_A(k0 + 64);  // prefetch next step's A

#pragma unroll
    for (int kk = 0; kk < 2; ++kk) {
#pragma unroll
      for (int n = 0; n < 8; ++n) {
        const int col = wc * 128 + n * 16 + q;
        const int sub = ((kk << 2) | half) ^ (col & 7);
        s16x8 bf = *(const s16x8*)&bufc[col * 64 + sub * 8];
        acc[0][n] = __builtin_amdgcn_mfma_f32_16x16x32_bf16(afrag[0][kk], bf,
                                                            acc[0][n], 0, 0, 0);
        acc[1][n] = __builtin_amdgcn_mfma_f32_16x16x32_bf16(afrag[1][kk], bf,
                                                            acc[1][n], 0, 0, 0);
      }
    }
    __syncthreads();  // drains next-step B glds + A regs; frees bufc
  }

  // ---- epilogue: bias + relu, h tile -> LDS (row-major [128][256], swizzled) ----
#pragma unroll
  for (int n = 0; n < 8; ++n) {
    const int col = wc * 128 + n * 16 + q;
    const float bias = b1[col];
#pragma unroll
    for (int m = 0; m < 2; ++m) {
      const int rl0 = wr * 32 + m * 16 + half * 4;
#pragma unroll
      for (int r = 0; r < 4; ++r) {
        const int rl = rl0 + r;
        float v = fmaxf(acc[m][n][r] + bias, 0.0f);
        const int ch = (col >> 3) ^ (rl & 7);
        smem[rl * 256 + ch * 8 + (col & 7)] = f2bf(v);
      }
    }
  }
  __syncthreads();

  // ---- GEMM2: out_tile[128][64] = h[128][256] @ w2t^T, 8 waves x 16 rows ----
  f32x4 acc2[4];
#pragma unroll
  for (int n = 0; n < 4; ++n) acc2[n] = z4;

  const int arow = wid * 16 + q;
#pragma unroll
  for (int ks = 0; ks < HIDDEN; ks += 32) {
    const int ch = ((ks >> 3) + half) ^ (q & 7);
    s16x8 a2 = *(const s16x8*)&smem[arow * 256 + ch * 8];
#pragma unroll
    for (int n = 0; n < 4; ++n) {
      const int c = n * 16 + q;
      s16x8 bf = *(const s16x8*)(w2t + (size_t)c * HIDDEN + ks + half * 8);
      acc2[n] = __builtin_amdgcn_mfma_f32_16x16x32_bf16(a2, bf, acc2[n], 0, 0, 0);
    }
  }

  float bias2[4];
#pragma unroll
  for (int n = 0; n < 4; ++n) {
    const int c = n * 16 + q;
    bias2[n] = (c < NCLS) ? b2[c] : 0.0f;
  }

#pragma unroll
  for (int r = 0; r < 4; ++r) {
    float vals[4];
    float mx = -1e30f;
#pragma unroll
    for (int n = 0; n < 4; ++n) {
      const int c = n * 16 + q;
      float v = acc2[n][r] + bias2[n];
      vals[n] = v;
      if (c < NCLS) mx = fmaxf(mx, v);
    }
    for (int off = 8; off >= 1; off >>= 1)
      mx = fmaxf(mx, __shfl_xor(mx, off, 64));
    float s = 0.f;
#pragma unroll
    for (int n = 0; n < 4; ++n) {
      const int c = n * 16 + q;
      if (c < NCLS) s += __expf(vals[n] - mx);
    }
    for (int off = 8; off >= 1; off >>= 1) s += __shfl_xor(s, off, 64);
    const float lz = __logf(s);
    const int rowg = bm * 128 + wid * 16 + half * 4 + r;
    if (rowg < NROWS) {
#pragma unroll
      for (int n = 0; n < 4; ++n) {
        const int c = n * 16 + q;
        if (c < NCLS) out[(size_t)rowg * NCLS + c] = vals[n] - mx - lz;
      }
    }
  }
}

extern "C" void kernel_launch(void* const* d_in, const int* in_sizes, int n_in,
                              void* d_out, int out_size, void* d_ws, size_t ws_size,
                              hipStream_t stream) {
  const float* x  = (const float*)d_in[0];
  // d_in[1] = edge_index: dead (ALPHA==1.0 makes APPNP the identity)
  const float* W1 = (const float*)d_in[2];
  const float* b1 = (const float*)d_in[3];
  const float* W2 = (const float*)d_in[4];
  const float* b2 = (const float*)d_in[5];
  float* out = (float*)d_out;

  char* ws = (char*)d_ws;
  unsigned short* w1t = (unsigned short*)(ws);           // 256 KB
  unsigned short* w2t = (unsigned short*)(ws + 262144);  // 32 KB

  prep_kernel<<<36, 256, 0, stream>>>(W1, W2, w1t, w2t);
  fused_kernel<<<(NROWS + 127) / 128, 512, 0, stream>>>(x, w1t, w2t, b1, b2, out);
}

// Round 3
// 66.358 us; speedup vs baseline: 2.2143x; 2.2143x over previous
//
#include <hip/hip_runtime.h>
#include <cstdint>
#include <cstddef>

#define NROWS 100000
#define FIN 512
#define HIDDEN 256
#define NCLS 50

typedef __attribute__((ext_vector_type(8))) short s16x8;
typedef __attribute__((ext_vector_type(4))) float f32x4;

// round-to-nearest-even fp32->bf16 (scalar)
__device__ __forceinline__ unsigned short f2bf(float f) {
  unsigned int u = __float_as_uint(f);
  u += 0x7fffu + ((u >> 16) & 1u);
  return (unsigned short)(u >> 16);
}

// packed fp32x2 -> bf16x2 (RNE) - single VALU op
__device__ __forceinline__ unsigned int cvt_pk_bf16(float lo, float hi) {
  unsigned int r;
  asm("v_cvt_pk_bf16_f32 %0, %1, %2" : "=v"(r) : "v"(lo), "v"(hi));
  return r;
}

__device__ __forceinline__ void gload_lds16(const void* g, void* l) {
  __builtin_amdgcn_global_load_lds(
      (const __attribute__((address_space(1))) void*)g,
      (__attribute__((address_space(3))) void*)l, 16, 0, 0);
}

__device__ __forceinline__ f32x4 mfma_bf16(s16x8 a, s16x8 b, f32x4 c) {
  return __builtin_amdgcn_mfma_f32_16x16x32_bf16(a, b, c, 0, 0, 0);
}

// prep: w1t[n][k] = bf16(W1[k][n])  [256][512]   (blocks 0..31, LDS transpose)
//       w2t[c][k] = bf16(W2[k][c]), c>=50 -> 0   [64][256]   (blocks 32..35)
__global__ __launch_bounds__(256) void prep_kernel(
    const float* __restrict__ W1, const float* __restrict__ W2,
    unsigned short* __restrict__ w1t, unsigned short* __restrict__ w2t) {
  __shared__ float tile[64][65];
  const int b = blockIdx.x, t = threadIdx.x;
  if (b < 32) {
    const int k0 = (b >> 2) * 64, n0 = (b & 3) * 64;
    const int rq = t >> 6, col = t & 63;
#pragma unroll
    for (int i = 0; i < 16; ++i) {
      int row = i * 4 + rq;
      tile[row][col] = W1[(size_t)(k0 + row) * HIDDEN + n0 + col];
    }
    __syncthreads();
#pragma unroll
    for (int i = 0; i < 16; ++i) {
      int n = i * 4 + rq;
      w1t[(size_t)(n0 + n) * FIN + k0 + col] = f2bf(tile[col][n]);
    }
  } else {
    const int b2i = b - 32;  // 0..3, k-range
#pragma unroll
    for (int i = 0; i < 16; ++i) {
      int idx = t + i * 256;          // 0..4095
      int c = idx >> 6;               // 0..63
      int k = b2i * 64 + (idx & 63);  // 0..255
      float v = (c < NCLS) ? W2[(size_t)k * NCLS + c] : 0.0f;
      w2t[(size_t)c * HIDDEN + k] = f2bf(v);
    }
  }
}

// Fused: out = log_softmax(relu(x@W1+b1) @ W2 + b2)
// 512 threads / 8 waves (4M x 2N), tile 128 rows x 256 cols, BK=32.
// A: fp32 via global_load_lds (pre-swizzled source, linear dest), dbuf 2x16KB.
// B: w1t bf16 via global_load_lds, dbuf 2x16KB.  Total LDS 64KB -> 2 blocks/CU.
// Convert fp32->bf16 at LDS-read with v_cvt_pk_bf16_f32.
// Epilogue: two-pass GEMM2 (h-half 32KB in A-region, w2t 32KB in B-region).
__global__ __launch_bounds__(512, 4) void fused_kernel(
    const float* __restrict__ x, const unsigned short* __restrict__ w1t,
    const unsigned short* __restrict__ w2t, const float* __restrict__ b1,
    const float* __restrict__ b2, float* __restrict__ out) {
  __shared__ char smem[65536];
  float* const Abase = (float*)smem;                          // 2 x 16KB fp32
  unsigned short* const Bbase = (unsigned short*)(smem + 32768);  // 2 x 16KB bf16

  const int t = threadIdx.x;
  const int lane = t & 63, wid = t >> 6;
  const int q = lane & 15, half = lane >> 4;
  const int wr = wid >> 1, wc = wid & 1;
  const int bm = blockIdx.x;

  // ---- staging: A tile [128 rows][32 f32] = 1024 chunks(16B), 2/thread ----
  // lds chunk (row,s) holds global chunk s^(row&7)  (128B-window permute)
  auto stage_A = [&](float* buf, int k0) {
#pragma unroll
    for (int i = 0; i < 2; ++i) {
      int c = t + i * 512;
      int row = c >> 3, s = c & 7;
      int grow = bm * 128 + row;
      if (grow > NROWS - 1) grow = NROWS - 1;
      gload_lds16(x + (size_t)grow * FIN + k0 + ((s ^ (row & 7)) << 2),
                  buf + c * 4);
    }
  };
  // ---- B tile [256 cols][32 bf16] = 1024 chunks, 2/thread ----
  // lds chunk (col,s) holds global chunk s^((col>>2)&3)  (64B-window permute)
  auto stage_B = [&](unsigned short* buf, int k0) {
#pragma unroll
    for (int i = 0; i < 2; ++i) {
      int c = t + i * 512;
      int col = c >> 2, s = c & 3;
      gload_lds16(w1t + (size_t)col * FIN + k0 + ((s ^ ((col >> 2) & 3)) << 3),
                  buf + c * 8);
    }
  };

  f32x4 acc[2][8];
  const f32x4 z4 = {0.f, 0.f, 0.f, 0.f};
#pragma unroll
  for (int m = 0; m < 2; ++m)
#pragma unroll
    for (int n = 0; n < 8; ++n) acc[m][n] = z4;

  stage_A(Abase, 0);
  stage_B(Bbase, 0);
  __syncthreads();

  for (int ks = 0; ks < 16; ++ks) {
    const int cur = ks & 1;
    float* Ac = Abase + cur * 4096;
    unsigned short* Bc = Bbase + cur * 8192;
    if (ks < 15) {
      stage_A(Abase + (cur ^ 1) * 4096, (ks + 1) * 32);
      stage_B(Bbase + (cur ^ 1) * 8192, (ks + 1) * 32);
    }

    // A fragments: row = wr*32+m*16+q, k = half*8..+8 (chunks half*2, half*2+1)
    s16x8 af[2];
#pragma unroll
    for (int m = 0; m < 2; ++m) {
      const int row = wr * 32 + m * 16 + q;
      const int cb = row * 8;
      f32x4 lo = *(const f32x4*)(Ac + (cb + ((half * 2) ^ (q & 7))) * 4);
      f32x4 hi = *(const f32x4*)(Ac + (cb + ((half * 2 + 1) ^ (q & 7))) * 4);
      union { unsigned int u[4]; s16x8 v; } cvu;
      cvu.u[0] = cvt_pk_bf16(lo[0], lo[1]);
      cvu.u[1] = cvt_pk_bf16(lo[2], lo[3]);
      cvu.u[2] = cvt_pk_bf16(hi[0], hi[1]);
      cvu.u[3] = cvt_pk_bf16(hi[2], hi[3]);
      af[m] = cvu.v;
    }

#pragma unroll
    for (int n = 0; n < 8; ++n) {
      const int col = wc * 128 + n * 16 + q;
      s16x8 bf = *(const s16x8*)(Bc + col * 32 + ((half ^ ((q >> 2) & 3)) << 3));
      acc[0][n] = mfma_bf16(af[0], bf, acc[0][n]);
      acc[1][n] = mfma_bf16(af[1], bf, acc[1][n]);
    }
    __syncthreads();
  }

  // ================= epilogue =================
  unsigned short* const hls = (unsigned short*)smem;   // [64][256] bf16, 32KB
  unsigned short* const wls = Bbase;                   // [64][256] bf16, 32KB
  const int p_of_wave = wid >> 2;  // waves 0-3 own rows 0-63, 4-7 own 64-127

  // stage w2t once (all threads): lds chunk (row,s) holds global chunk s^(row&7)
#pragma unroll
  for (int i = 0; i < 4; ++i) {
    int c = t + i * 512;
    int row = c >> 5, s = c & 31;
    gload_lds16(w2t + (size_t)row * HIDDEN + ((s ^ (row & 7)) << 3), wls + c * 8);
  }

  // h-write lambda: local row rl in 0..63, swizzle ch = (col>>3)^(rl&7)
  auto write_h = [&]() {
#pragma unroll
    for (int n = 0; n < 8; ++n) {
      const int col = wc * 128 + n * 16 + q;
      const float bias = b1[col];
      const int chs = col & 7;
#pragma unroll
      for (int m = 0; m < 2; ++m) {
        const int rl0 = (wr & 1) * 32 + m * 16 + half * 4;
#pragma unroll
        for (int r = 0; r < 4; ++r) {
          const int rl = rl0 + r;
          float v = fmaxf(acc[m][n][r] + bias, 0.0f);
          const int ch = (col >> 3) ^ (rl & 7);
          hls[rl * 256 + ch * 8 + chs] = f2bf(v);
        }
      }
    }
  };

  // GEMM2 pass over 64 rows by 4 waves (aw = wid&3): 16 rows x 64 cols each
  auto gemm2_pass = [&](int p) {
    f32x4 acc2[4];
#pragma unroll
    for (int n = 0; n < 4; ++n) acc2[n] = z4;
    const int arl = (wid & 3) * 16 + q;
#pragma unroll
    for (int ks = 0; ks < HIDDEN; ks += 32) {
      const int g = (ks >> 3) + half;
      s16x8 a2 = *(const s16x8*)(hls + arl * 256 + ((g ^ (arl & 7)) << 3));
#pragma unroll
      for (int n = 0; n < 4; ++n) {
        const int c = n * 16 + q;
        s16x8 b2f = *(const s16x8*)(wls + c * 256 + ((g ^ (c & 7)) << 3));
        acc2[n] = mfma_bf16(a2, b2f, acc2[n]);
      }
    }
    float bias2[4];
#pragma unroll
    for (int n = 0; n < 4; ++n) {
      const int c = n * 16 + q;
      bias2[n] = (c < NCLS) ? b2[c] : 0.0f;
    }
#pragma unroll
    for (int r = 0; r < 4; ++r) {
      float vals[4];
      float mx = -1e30f;
#pragma unroll
      for (int n = 0; n < 4; ++n) {
        const int c = n * 16 + q;
        float v = acc2[n][r] + bias2[n];
        vals[n] = v;
        if (c < NCLS) mx = fmaxf(mx, v);
      }
      for (int off = 8; off >= 1; off >>= 1)
        mx = fmaxf(mx, __shfl_xor(mx, off, 64));
      float s = 0.f;
#pragma unroll
      for (int n = 0; n < 4; ++n) {
        const int c = n * 16 + q;
        if (c < NCLS) s += __expf(vals[n] - mx);
      }
      for (int off = 8; off >= 1; off >>= 1) s += __shfl_xor(s, off, 64);
      const float lz = __logf(s);
      const int rowg = bm * 128 + p * 64 + (wid & 3) * 16 + half * 4 + r;
      if (rowg < NROWS) {
#pragma unroll
        for (int n = 0; n < 4; ++n) {
          const int c = n * 16 + q;
          if (c < NCLS) out[(size_t)rowg * NCLS + c] = vals[n] - mx - lz;
        }
      }
    }
  };

  if (p_of_wave == 0) write_h();   // h rows 0..63
  __syncthreads();                 // drains w2t glds + h writes
  if (p_of_wave == 0) gemm2_pass(0);
  __syncthreads();                 // pass-0 reads done
  if (p_of_wave == 1) write_h();   // h rows 64..127 overwrite hls
  __syncthreads();
  if (p_of_wave == 1) gemm2_pass(1);
}

extern "C" void kernel_launch(void* const* d_in, const int* in_sizes, int n_in,
                              void* d_out, int out_size, void* d_ws, size_t ws_size,
                              hipStream_t stream) {
  const float* x  = (const float*)d_in[0];
  // d_in[1] = edge_index: dead (ALPHA==1.0 makes APPNP the identity)
  const float* W1 = (const float*)d_in[2];
  const float* b1 = (const float*)d_in[3];
  const float* W2 = (const float*)d_in[4];
  const float* b2 = (const float*)d_in[5];
  float* out = (float*)d_out;

  char* ws = (char*)d_ws;
  unsigned short* w1t = (unsigned short*)(ws);           // 256 KB
  unsigned short* w2t = (unsigned short*)(ws + 262144);  // 32 KB

  prep_kernel<<<36, 256, 0, stream>>>(W1, W2, w1t, w2t);
  fused_kernel<<<(NROWS + 127) / 128, 512, 0, stream>>>(x, w1t, w2t, b1, b2, out);
}